// Round 2
// baseline (59.856 us; speedup 1.0000x reference)
//
#include <hip/hip_runtime.h>

// Round 2: single fused kernel. Per-quad row processing (coalesced float4),
// reciprocal-table instead of fdiv, unroll x2, block-level atomicAdd finale
// (d_out zeroed via memset node each replay). 268 MB mandatory traffic.

__device__ __forceinline__ void row_contrib(float4 l, float4 o, int c0, int q,
                                            float& acc) {
    // lab0 lives in lane q==0 of each 4-lane quad (l.x). Broadcast within quad.
    float lab0 = __shfl(l.x, 0, 4);

    int r = (int)rintf(3.0f * lab0);  // round-half-even, matches jnp.round
    int n; float inv;
    if (lab0 == 0.0f) { n = 1; inv = 1.0f; }
    else if (r == 1)  { n = 3; inv = 0x1.555556p-2f; }   // 1/3
    else if (r == 2)  { n = 6; inv = 0x1.555556p-3f; }   // 1/6
    else if (r == 3)  { n = 9; inv = 0x1.c71c72p-4f; }   // 1/9
    else              { n = 0; inv = 0.0f; }

    float dx = o.x - l.x;
    float dy = o.y - l.y;
    float dz = o.z - l.z;
    float dw = o.w - l.w;

    float s = 0.0f;
    s += (c0 + 0 < n) ? dx * dx : 0.0f;
    s += (c0 + 1 < n) ? dy * dy : 0.0f;
    s += (c0 + 2 < n) ? dz * dz : 0.0f;
    s += (c0 + 3 < n) ? dw * dw : 0.0f;

    // quad reduction: lane q==0 ends with the row's masked sum
    s += __shfl_xor(s, 1, 4);
    s += __shfl_xor(s, 2, 4);

    if (q == 0) acc += s * inv;
}

__global__ __launch_bounds__(256) void mse2_fused(
    const float4* __restrict__ O4, const float4* __restrict__ L4,
    float* __restrict__ out, int n4, float inv_b)
{
    const int tid    = blockIdx.x * blockDim.x + threadIdx.x;
    const int stride = gridDim.x * blockDim.x;
    const int q  = threadIdx.x & 3;
    const int c0 = q * 4;

    float acc = 0.0f;

    for (int g = tid; g < n4; g += 2 * stride) {
        // two independent load pairs in flight per iteration
        float4 l0 = L4[g];
        float4 o0 = O4[g];
        const int g1 = g + stride;
        const bool has1 = (g1 < n4);
        float4 l1 = make_float4(0.f, 0.f, 0.f, 0.f);
        float4 o1 = make_float4(0.f, 0.f, 0.f, 0.f);
        if (has1) { l1 = L4[g1]; o1 = O4[g1]; }

        row_contrib(l0, o0, c0, q, acc);
        if (has1) row_contrib(l1, o1, c0, q, acc);
    }

    // wave64 reduction
    #pragma unroll
    for (int off = 32; off >= 1; off >>= 1)
        acc += __shfl_down(acc, off, 64);

    __shared__ float red[4];
    const int wave = threadIdx.x >> 6;
    if ((threadIdx.x & 63) == 0) red[wave] = acc;
    __syncthreads();

    if (threadIdx.x == 0)
        atomicAdd(out, (red[0] + red[1] + red[2] + red[3]) * inv_b);
}

extern "C" void kernel_launch(void* const* d_in, const int* in_sizes, int n_in,
                              void* d_out, int out_size, void* d_ws, size_t ws_size,
                              hipStream_t stream) {
    const float* outputs = (const float*)d_in[0];
    const float* labels  = (const float*)d_in[1];

    const int total = in_sizes[0];   // B * 16
    const int n4    = total / 4;     // number of float4 elements
    const int b     = total / 16;    // number of rows

    // d_out accumulates via atomics -> must be zeroed every call (graph memset node)
    hipMemsetAsync(d_out, 0, sizeof(float) * out_size, stream);

    mse2_fused<<<2048, 256, 0, stream>>>(
        (const float4*)outputs, (const float4*)labels,
        (float*)d_out, n4, 1.0f / (float)b);
    (void)d_ws; (void)ws_size; (void)n_in;
}